// Round 7
// baseline (576.528 us; speedup 1.0000x reference)
//
#include <hip/hip_runtime.h>
#include <hip/hip_bf16.h>
#include <stdint.h>

// Problem constants
#define TOK    8192      // B*S
#define DIN    4096
#define DOUT   4096
#define NEXP   8
#define RK     16
#define NRANK  128       // NEXP*RK
#define KE     4224      // DIN + NRANK (extended K)
#define SEQB   2048      // S (tokens per batch entry)
#define LSCALE 2.0f      // ALPHA/RANK
#define KSPLIT 4
#define KSLICE (DIN / KSPLIT)   // 1024

typedef __attribute__((ext_vector_type(8))) short bf8_t;    // 8 bf16 = 4 VGPRs
typedef __attribute__((ext_vector_type(4))) float f4_t;
typedef __attribute__((ext_vector_type(16))) float f16v;    // 32x32 MFMA acc

__device__ __forceinline__ void async_copy16(const void* g, void* l) {
  __builtin_amdgcn_global_load_lds((const __attribute__((address_space(1))) void*)g,
                                   (__attribute__((address_space(3))) void*)l,
                                   16, 0, 0);
}

__device__ __forceinline__ ushort f2bf(float f) {
  __hip_bfloat16 h = __float2bfloat16(f);
  return *reinterpret_cast<ushort*>(&h);
}

// ---------- fused conversion kernel (fp32 -> bf16, memory-bound) ----------
#define R0 (TOK * DIN / 8)        // 4,194,304
#define R1 (DOUT * DIN / 8)       // 2,097,152
#define R2 (DOUT * NEXP * 2)      //    65,536
#define R3 (NRANK * DIN / 8)      //    65,536
#define RTOT (R0 + R1 + R2 + R3)  // 6,422,528  (= 25088 * 256)

__global__ __launch_bounds__(256)
void cvt_all_kernel(const float* __restrict__ x, const float* __restrict__ wb,
                    const float* __restrict__ lu, const float* __restrict__ ld,
                    ushort* __restrict__ Xe, ushort* __restrict__ Wc,
                    ushort* __restrict__ Ldb) {
  int i = blockIdx.x * 256 + threadIdx.x;
  const float* src;
  ushort* dst;
  if (i < R0) {
    int t = i >> 9;                    // DIN/8 = 512
    int c = (i & 511) * 8;
    src = x + (size_t)t * DIN + c;
    dst = Xe + (size_t)t * KE + c;
  } else if (i < R0 + R1) {
    int j = i - R0;
    int t = j >> 9;
    int c = (j & 511) * 8;
    src = wb + (size_t)t * DIN + c;
    dst = Wc + (size_t)t * KE + c;
  } else if (i < R0 + R1 + R2) {
    int j = i - (R0 + R1);
    int o = j >> 4;
    int rem = j & 15;
    int n = rem >> 1;
    int half = rem & 1;
    src = lu + ((size_t)n * DOUT + o) * RK + half * 8;
    dst = Wc + (size_t)o * KE + DIN + n * RK + half * 8;
  } else {
    int j = i - (R0 + R1 + R2);
    src = ld + (size_t)j * 8;
    dst = Ldb + (size_t)j * 8;
  }
  const float4* s = reinterpret_cast<const float4*>(src);
  float4 a = s[0], b = s[1];
  union { ushort u[8]; uint4 v; } o;
  o.u[0]=f2bf(a.x); o.u[1]=f2bf(a.y); o.u[2]=f2bf(a.z); o.u[3]=f2bf(a.w);
  o.u[4]=f2bf(b.x); o.u[5]=f2bf(b.y); o.u[6]=f2bf(b.z); o.u[7]=f2bf(b.w);
  *reinterpret_cast<uint4*>(dst) = o.v;
}

// ---------- 128x128 bf16 MFMA GEMM (m97 structure) — down-projection only ----------
template<int KLEN, int LDB, int MODE>
__global__ __launch_bounds__(256)
void gemm128(const ushort* __restrict__ A,
             const ushort* __restrict__ Bm,
             float* __restrict__ C) {
  __shared__ __align__(16) ushort As[128 * 32];
  __shared__ __align__(16) ushort Bs[128 * 32];

  const int tid  = threadIdx.x;
  const int wave = tid >> 6;
  const int lane = tid & 63;

  int bm, bn;
  if (MODE == 0) {
    int bid = blockIdx.x;
    int xcd = bid & 7;
    int idx = bid >> 3;
    int nt  = xcd * 4 + (idx & 3);
    int mt  = idx >> 2;
    bm = mt * 128;
    bn = nt * 128;
  } else {
    bm = blockIdx.y * 128;
    bn = blockIdx.x * 128;
  }
  const int wm = wave & 1, wn = wave >> 1;

  f4_t acc[4][4];
#pragma unroll
  for (int i = 0; i < 4; i++)
#pragma unroll
    for (int j = 0; j < 4; j++) acc[i][j] = (f4_t){0.f, 0.f, 0.f, 0.f};

  const int f0 = tid * 8;
  const int r0 = f0 >> 5, c0 = f0 & 31;
  const int f1 = (256 + tid) * 8;
  const int r1 = f1 >> 5, c1 = f1 & 31;
  const int l0 = (wave << 6) * 8;
  const int l1 = (256 + (wave << 6)) * 8;

  const ushort* Ar = As + (wm * 64 + (lane & 15)) * 32 + (lane >> 4) * 8;
  const ushort* Br = Bs + (wn * 64 + (lane & 15)) * 32 + (lane >> 4) * 8;

  const int kbase = (MODE == 1) ? blockIdx.z * KSLICE : 0;
  const int kend  = kbase + KLEN;

  for (int k0 = kbase; k0 < kend; k0 += 32) {
    __syncthreads();
    async_copy16(A  + (size_t)(bm + r0) * KE  + k0 + c0, (void*)(As + l0));
    async_copy16(A  + (size_t)(bm + r1) * KE  + k0 + c1, (void*)(As + l1));
    async_copy16(Bm + (size_t)(bn + r0) * LDB + k0 + c0, (void*)(Bs + l0));
    async_copy16(Bm + (size_t)(bn + r1) * LDB + k0 + c1, (void*)(Bs + l1));
    __syncthreads();
    bf8_t av[4], bv[4];
#pragma unroll
    for (int i = 0; i < 4; i++) av[i] = *(const bf8_t*)(Ar + i * 16 * 32);
#pragma unroll
    for (int j = 0; j < 4; j++) bv[j] = *(const bf8_t*)(Br + j * 16 * 32);
#pragma unroll
    for (int i = 0; i < 4; i++)
#pragma unroll
      for (int j = 0; j < 4; j++)
        acc[i][j] = __builtin_amdgcn_mfma_f32_16x16x32_bf16(av[i], bv[j], acc[i][j], 0, 0, 0);
  }

  if (MODE == 0) {
#pragma unroll
    for (int i = 0; i < 4; i++) {
      int row = bm + wm * 64 + i * 16 + (lane >> 4) * 4;
#pragma unroll
      for (int j = 0; j < 4; j++) {
        int col = bn + wn * 64 + j * 16 + (lane & 15);
#pragma unroll
        for (int rr = 0; rr < 4; rr++)
          C[(size_t)(row + rr) * DOUT + col] = acc[i][j][rr];
      }
    }
  } else {
    float* Dz = C + (size_t)blockIdx.z * TOK * NRANK;
#pragma unroll
    for (int i = 0; i < 4; i++) {
      int row = bm + wm * 64 + i * 16 + (lane >> 4) * 4;
#pragma unroll
      for (int j = 0; j < 4; j++) {
        int col = wn * 64 + j * 16 + (lane & 15);
#pragma unroll
        for (int rr = 0; rr < 4; rr++)
          Dz[(size_t)(row + rr) * NRANK + col] = acc[i][j][rr];
      }
    }
  }
}

// reduce split-K slices, scale by routing*LSCALE, pack bf16 into Xe extension cols
__global__ void scale_store_kernel(const float* __restrict__ D32,
                                   const float* __restrict__ rw,
                                   ushort* __restrict__ Xe) {
  int i = blockIdx.x * 256 + threadIdx.x;          // [0, TOK*NRANK/4)
  int t = i >> 5;                                  // token
  int g = (i & 31) * 4;                            // col base (4 cols, same expert)
  size_t base = (size_t)t * NRANK + g;
  const size_t ss = (size_t)TOK * NRANK;
  float4 a = *reinterpret_cast<const float4*>(D32 + base);
  float4 b = *reinterpret_cast<const float4*>(D32 + ss + base);
  float4 c = *reinterpret_cast<const float4*>(D32 + 2 * ss + base);
  float4 d = *reinterpret_cast<const float4*>(D32 + 3 * ss + base);
  int n = g >> 4;                                  // expert index
  int bb = t / SEQB;
  float s = rw[bb * NEXP + n] * LSCALE;
  union { ushort u[4]; uint2 v; } o;
  o.u[0] = f2bf((a.x + b.x + c.x + d.x) * s);
  o.u[1] = f2bf((a.y + b.y + c.y + d.y) * s);
  o.u[2] = f2bf((a.z + b.z + c.z + d.z) * s);
  o.u[3] = f2bf((a.w + b.w + c.w + d.w) * s);
  *reinterpret_cast<uint2*>(Xe + (size_t)t * KE + DIN + g) = o.v;
}

// ---------- 256x256 bf16 GEMM, r5 schedule + 32x32x16 MFMA engine ----------
// C[m,n] = sum_k A[m,k]*B[n,k], A:[TOK,KE], B:[DOUT,KE] (B^T), fp32 out.
// BUGFIX of round 6: the swizzle XOR must apply to the COMPLETE logical
// byte address. r6 pre-added the lane base (containing hi<<4 and the row
// LSB at bit 6 — exactly the bits xorb flips) to the POINTER and XOR'd
// only the remainder: add-after-XOR carries corrupted bits 4-6 for half
// the lanes (absmax 86). Now: addr = ((row<<6) + hi*16 + ks*32) ^ xorb,
// pointer un-offset. (Terms of the sum are bit-disjoint; XOR is last.)
// Experiment vs r5 (single lever, unchanged from r6's intent): engine
// 16x16x32 (32 MFMA/window) -> 32x32x16 (16 MFMA/window). m119/m06: 32x32
// sustains 2382-2495 TF vs 2075-2176, and halved instruction count cuts
// issue pressure in the setprio cluster. Phases split by k-slice (ks=0/1),
// uniform 6-read phases (4 A + 2 B frags).
// All r5 scaffolding verbatim: ring-4 LDS slots, 3-tile prefetch,
// vmcnt(8)->4->0 cadence, rectangular XCD map (FETCH 203 MB), staging
// involution (0 bank conflicts), barrier/lgkm/setprio phase pattern.
// A-operand layout: lane row = lane&31, 8 k-elems at (lane>>5)*8 within
// the 16-wide slice; B symmetric (any within-slice k-permutation is shared
// by A and B and cancels in the dot product). C/D layout (m74/m101):
// col = lane&31, row = (reg&3) + 8*(reg>>2) + 4*(lane>>5), reg 0..15.
#define BK32  32
#define NT132 (KE / BK32)    // 132

__global__ __launch_bounds__(512, 2)
void gemm256(const ushort* __restrict__ A, const ushort* __restrict__ Bm,
             float* __restrict__ C) {
  __shared__ __align__(16) ushort As[4][256 * 32];   // 64 KiB
  __shared__ __align__(16) ushort Bs[4][256 * 32];   // 64 KiB

  const int tid  = threadIdx.x;
  const int w    = tid >> 6;        // wave 0..7
  const int lane = tid & 63;
  const int wm   = w >> 2;          // 0..1  (M half)
  const int wn   = w & 3;           // 0..3  (N quarter)

  // XCD-aware rectangular chunks (round-2 proven: FETCH 557->203 MB).
  const int bid = blockIdx.x;
  const int xg  = bid & 7;
  const int jj  = bid >> 3;                            // 0..63
  const int bm  = (((xg & 3) << 3) + (jj & 7)) << 8;   // mi*256, mi 0..31
  const int bn  = (((xg >> 2) << 3) + (jj >> 3)) << 8; // ni*256, ni 0..15

  f16v acc[4][2];
#pragma unroll
  for (int i = 0; i < 4; ++i)
#pragma unroll
    for (int q = 0; q < 2; ++q)
#pragma unroll
      for (int e = 0; e < 16; ++e) acc[i][q][e] = 0.f;

  // ---- 32x32 frag-read geometry (swizzled) ----
  const int rl   = lane & 31;
  const int hi   = lane >> 5;
  const int xorb = ((rl >> 1) & 7) << 4;
  // full logical lane base (row LSB and hi<<4 INSIDE the XOR expression):
  const int albase = ((wm * 128 + rl) << 6) + (hi << 4);  // A rows at wm*128
  const int blbase = ((wn * 64 + rl) << 6) + (hi << 4);   // B rows at wn*64

#define RD32(LS, lb_, f_, ks_) \
  (*(const bf8_t*)((const char*)(LS) + (((lb_) + (f_) * 2048 + (ks_) * 32) ^ xorb)))

  // ---- staging geometry (per-thread, tile = 256x32 bf16 = 16 KiB; proven) ----
  const int sxr = (lane >> 3) << 4;
  const int t0  = (w << 10) + (lane << 4);
  const int l0b = t0 ^ sxr;
  const int l1b = (t0 + 8192) ^ sxr;
  const size_t goff0 = (size_t)(l0b >> 6) * KE + ((l0b & 63) >> 1); // elements
  const size_t goff1 = (size_t)(l1b >> 6) * KE + ((l1b & 63) >> 1);
  const int ld0 = (w << 9);          // LDS dest base, elements
  const int ld1 = (w << 9) + 4096;

  const ushort* Ap = A  + (size_t)bm * KE;
  const ushort* Bp = Bm + (size_t)bn * KE;

#define STAGE_A256(kt, buf) do {                                   \
    const ushort* cp_ = Ap + (size_t)(kt) * BK32;                  \
    async_copy16(cp_ + goff0, (void*)(As[buf] + ld0));             \
    async_copy16(cp_ + goff1, (void*)(As[buf] + ld1));             \
  } while (0)
#define STAGE_B256(kt, buf) do {                                   \
    const ushort* cp_ = Bp + (size_t)(kt) * BK32;                  \
    async_copy16(cp_ + goff0, (void*)(Bs[buf] + ld0));             \
    async_copy16(cp_ + goff1, (void*)(Bs[buf] + ld1));             \
  } while (0)

  // prologue: stage tiles 0,1,2 into ring slots 0,1,2 (12 loads/thread).
  STAGE_A256(0, 0); STAGE_B256(0, 0);
  STAGE_A256(1, 1); STAGE_B256(1, 1);
  STAGE_A256(2, 2); STAGE_B256(2, 2);
  asm volatile("s_waitcnt vmcnt(8)" ::: "memory");   // tile 0 landed; 1,2 in flight
  __builtin_amdgcn_s_barrier();

  for (int T = 0; T < NT132; ++T) {
    const int b  = T & 3;
    const int sb = (T + 3) & 3;
    const char* Ab = (const char*)As[b];
    const char* Bb = (const char*)Bs[b];
    bf8_t av[4], bv[2];

    // ---- phase 0 (ks=0): 6 reads; stage A-tile T+3; 8 MFMA ----
#pragma unroll
    for (int f = 0; f < 4; ++f) av[f] = RD32(Ab, albase, f, 0);
#pragma unroll
    for (int g = 0; g < 2; ++g) bv[g] = RD32(Bb, blbase, g, 0);
    if (T + 3 < NT132) STAGE_A256(T + 3, sb);
    __builtin_amdgcn_s_barrier();
    asm volatile("s_waitcnt lgkmcnt(0)" ::: "memory");
    __builtin_amdgcn_s_setprio(1);
#pragma unroll
    for (int f = 0; f < 4; ++f)
#pragma unroll
      for (int g = 0; g < 2; ++g)
        acc[f][g] = __builtin_amdgcn_mfma_f32_32x32x16_bf16(av[f], bv[g], acc[f][g], 0, 0, 0);
    __builtin_amdgcn_s_setprio(0);
    __builtin_amdgcn_s_barrier();

    // ---- phase 1 (ks=1): 6 reads; stage B-tile T+3; 8 MFMA ----
#pragma unroll
    for (int f = 0; f < 4; ++f) av[f] = RD32(Ab, albase, f, 1);
#pragma unroll
    for (int g = 0; g < 2; ++g) bv[g] = RD32(Bb, blbase, g, 1);
    if (T + 3 < NT132) STAGE_B256(T + 3, sb);
    __builtin_amdgcn_s_barrier();
    asm volatile("s_waitcnt lgkmcnt(0)" ::: "memory");
    __builtin_amdgcn_s_setprio(1);
#pragma unroll
    for (int f = 0; f < 4; ++f)
#pragma unroll
      for (int g = 0; g < 2; ++g)
        acc[f][g] = __builtin_amdgcn_mfma_f32_32x32x16_bf16(av[f], bv[g], acc[f][g], 0, 0, 0);
    __builtin_amdgcn_s_setprio(0);
    // counted vmcnt once per tile: keep the 8 newest loads (tiles T+2, T+3)
    // in flight; guarantees tile T+1 is fully in LDS before its phase-0 reads.
    if (T < NT132 - 3)       asm volatile("s_waitcnt vmcnt(8)" ::: "memory");
    else if (T == NT132 - 3) asm volatile("s_waitcnt vmcnt(4)" ::: "memory");
    else if (T == NT132 - 2) asm volatile("s_waitcnt vmcnt(0)" ::: "memory");
    __builtin_amdgcn_s_barrier();
  }

  // epilogue: fp32 C write (32x32 C/D layout, m74/m101-verified:
  // col = lane&31, row = (reg&3) + 8*(reg>>2) + 4*(lane>>5))
#pragma unroll
  for (int fm = 0; fm < 4; ++fm)
#pragma unroll
    for (int fn = 0; fn < 2; ++fn)
#pragma unroll
      for (int r = 0; r < 16; ++r) {
        int row = bm + wm * 128 + fm * 32 + (r & 3) + 8 * (r >> 2) + 4 * hi;
        int col = bn + wn * 64 + fn * 32 + rl;
        C[(size_t)row * DOUT + col] = acc[fm][fn][r];
      }
#undef STAGE_A256
#undef STAGE_B256
#undef RD32
}

extern "C" void kernel_launch(void* const* d_in, const int* in_sizes, int n_in,
                              void* d_out, int out_size, void* d_ws, size_t ws_size,
                              hipStream_t stream) {
  const float* x  = (const float*)d_in[0];
  const float* rw = (const float*)d_in[1];
  const float* wb = (const float*)d_in[2];
  const float* ld = (const float*)d_in[3];
  const float* lu = (const float*)d_in[4];
  float* out = (float*)d_out;

  // workspace layout (bf16 elements unless noted)
  ushort* Xe  = (ushort*)d_ws;                         // TOK*KE
  ushort* Wc  = Xe + (size_t)TOK * KE;                 // DOUT*KE
  ushort* Ldb = Wc + (size_t)DOUT * KE;                // NRANK*DIN
  float*  D32 = (float*)(Ldb + (size_t)NRANK * DIN);   // KSPLIT*TOK*NRANK fp32

  // one fused conversion dispatch (x, W_base, lora_up, lora_down -> bf16)
  cvt_all_kernel<<<RTOT / 256, 256, 0, stream>>>(x, wb, lu, ld, Xe, Wc, Ldb);

  // down-projection: D32[z] = Xe[:, z*1024:(z+1)*1024] @ Ld^T   (split-K)
  gemm128<KSLICE, DIN, 1><<<dim3(1, TOK / 128, KSPLIT), 256, 0, stream>>>(Xe, Ldb, D32);
  // reduce + routing scale + pack into Xe extension columns
  scale_store_kernel<<<TOK * NRANK / 4 / 256, 256, 0, stream>>>(D32, rw, Xe);
  // main GEMM: out = Xe[TOK,KE] @ Wc[DOUT,KE]^T  (256x256, 32x32x16 engine)
  gemm256<<<dim3((TOK / 256) * (DOUT / 256)), 512, 0, stream>>>(Xe, Wc, out);
}

// Round 8
// 557.705 us; speedup vs baseline: 1.0338x; 1.0338x over previous
//
#include <hip/hip_runtime.h>
#include <hip/hip_bf16.h>
#include <stdint.h>

// Problem constants
#define TOK    8192      // B*S
#define DIN    4096
#define DOUT   4096
#define NEXP   8
#define RK     16
#define NRANK  128       // NEXP*RK
#define KE     4224      // DIN + NRANK (extended K)
#define SEQB   2048      // S (tokens per batch entry)
#define LSCALE 2.0f      // ALPHA/RANK
#define KSPLIT 4
#define KSLICE (DIN / KSPLIT)   // 1024

typedef __attribute__((ext_vector_type(8))) short bf8_t;   // 8 bf16 = 4 VGPRs
typedef __attribute__((ext_vector_type(4))) float f4_t;

__device__ __forceinline__ void async_copy16(const void* g, void* l) {
  __builtin_amdgcn_global_load_lds((const __attribute__((address_space(1))) void*)g,
                                   (__attribute__((address_space(3))) void*)l,
                                   16, 0, 0);
}

__device__ __forceinline__ ushort f2bf(float f) {
  __hip_bfloat16 h = __float2bfloat16(f);
  return *reinterpret_cast<ushort*>(&h);
}

// ---------- fused conversion kernel (fp32 -> bf16, memory-bound) ----------
#define R0 (TOK * DIN / 8)        // 4,194,304
#define R1 (DOUT * DIN / 8)       // 2,097,152
#define R2 (DOUT * NEXP * 2)      //    65,536
#define R3 (NRANK * DIN / 8)      //    65,536
#define RTOT (R0 + R1 + R2 + R3)  // 6,422,528  (= 25088 * 256)

__global__ __launch_bounds__(256)
void cvt_all_kernel(const float* __restrict__ x, const float* __restrict__ wb,
                    const float* __restrict__ lu, const float* __restrict__ ld,
                    ushort* __restrict__ Xe, ushort* __restrict__ Wc,
                    ushort* __restrict__ Ldb) {
  int i = blockIdx.x * 256 + threadIdx.x;
  const float* src;
  ushort* dst;
  if (i < R0) {
    int t = i >> 9;                    // DIN/8 = 512
    int c = (i & 511) * 8;
    src = x + (size_t)t * DIN + c;
    dst = Xe + (size_t)t * KE + c;
  } else if (i < R0 + R1) {
    int j = i - R0;
    int t = j >> 9;
    int c = (j & 511) * 8;
    src = wb + (size_t)t * DIN + c;
    dst = Wc + (size_t)t * KE + c;
  } else if (i < R0 + R1 + R2) {
    int j = i - (R0 + R1);
    int o = j >> 4;
    int rem = j & 15;
    int n = rem >> 1;
    int half = rem & 1;
    src = lu + ((size_t)n * DOUT + o) * RK + half * 8;
    dst = Wc + (size_t)o * KE + DIN + n * RK + half * 8;
  } else {
    int j = i - (R0 + R1 + R2);
    src = ld + (size_t)j * 8;
    dst = Ldb + (size_t)j * 8;
  }
  const float4* s = reinterpret_cast<const float4*>(src);
  float4 a = s[0], b = s[1];
  union { ushort u[8]; uint4 v; } o;
  o.u[0]=f2bf(a.x); o.u[1]=f2bf(a.y); o.u[2]=f2bf(a.z); o.u[3]=f2bf(a.w);
  o.u[4]=f2bf(b.x); o.u[5]=f2bf(b.y); o.u[6]=f2bf(b.z); o.u[7]=f2bf(b.w);
  *reinterpret_cast<uint4*>(dst) = o.v;
}

// ---------- 128x128 bf16 MFMA GEMM (m97 structure) — down-projection only ----------
template<int KLEN, int LDB, int MODE>
__global__ __launch_bounds__(256)
void gemm128(const ushort* __restrict__ A,
             const ushort* __restrict__ Bm,
             float* __restrict__ C) {
  __shared__ __align__(16) ushort As[128 * 32];
  __shared__ __align__(16) ushort Bs[128 * 32];

  const int tid  = threadIdx.x;
  const int wave = tid >> 6;
  const int lane = tid & 63;

  int bm, bn;
  if (MODE == 0) {
    int bid = blockIdx.x;
    int xcd = bid & 7;
    int idx = bid >> 3;
    int nt  = xcd * 4 + (idx & 3);
    int mt  = idx >> 2;
    bm = mt * 128;
    bn = nt * 128;
  } else {
    bm = blockIdx.y * 128;
    bn = blockIdx.x * 128;
  }
  const int wm = wave & 1, wn = wave >> 1;

  f4_t acc[4][4];
#pragma unroll
  for (int i = 0; i < 4; i++)
#pragma unroll
    for (int j = 0; j < 4; j++) acc[i][j] = (f4_t){0.f, 0.f, 0.f, 0.f};

  const int f0 = tid * 8;
  const int r0 = f0 >> 5, c0 = f0 & 31;
  const int f1 = (256 + tid) * 8;
  const int r1 = f1 >> 5, c1 = f1 & 31;
  const int l0 = (wave << 6) * 8;
  const int l1 = (256 + (wave << 6)) * 8;

  const ushort* Ar = As + (wm * 64 + (lane & 15)) * 32 + (lane >> 4) * 8;
  const ushort* Br = Bs + (wn * 64 + (lane & 15)) * 32 + (lane >> 4) * 8;

  const int kbase = (MODE == 1) ? blockIdx.z * KSLICE : 0;
  const int kend  = kbase + KLEN;

  for (int k0 = kbase; k0 < kend; k0 += 32) {
    __syncthreads();
    async_copy16(A  + (size_t)(bm + r0) * KE  + k0 + c0, (void*)(As + l0));
    async_copy16(A  + (size_t)(bm + r1) * KE  + k0 + c1, (void*)(As + l1));
    async_copy16(Bm + (size_t)(bn + r0) * LDB + k0 + c0, (void*)(Bs + l0));
    async_copy16(Bm + (size_t)(bn + r1) * LDB + k0 + c1, (void*)(Bs + l1));
    __syncthreads();
    bf8_t av[4], bv[4];
#pragma unroll
    for (int i = 0; i < 4; i++) av[i] = *(const bf8_t*)(Ar + i * 16 * 32);
#pragma unroll
    for (int j = 0; j < 4; j++) bv[j] = *(const bf8_t*)(Br + j * 16 * 32);
#pragma unroll
    for (int i = 0; i < 4; i++)
#pragma unroll
      for (int j = 0; j < 4; j++)
        acc[i][j] = __builtin_amdgcn_mfma_f32_16x16x32_bf16(av[i], bv[j], acc[i][j], 0, 0, 0);
  }

  if (MODE == 0) {
#pragma unroll
    for (int i = 0; i < 4; i++) {
      int row = bm + wm * 64 + i * 16 + (lane >> 4) * 4;
#pragma unroll
      for (int j = 0; j < 4; j++) {
        int col = bn + wn * 64 + j * 16 + (lane & 15);
#pragma unroll
        for (int rr = 0; rr < 4; rr++)
          C[(size_t)(row + rr) * DOUT + col] = acc[i][j][rr];
      }
    }
  } else {
    float* Dz = C + (size_t)blockIdx.z * TOK * NRANK;
#pragma unroll
    for (int i = 0; i < 4; i++) {
      int row = bm + wm * 64 + i * 16 + (lane >> 4) * 4;
#pragma unroll
      for (int j = 0; j < 4; j++) {
        int col = wn * 64 + j * 16 + (lane & 15);
#pragma unroll
        for (int rr = 0; rr < 4; rr++)
          Dz[(size_t)(row + rr) * NRANK + col] = acc[i][j][rr];
      }
    }
  }
}

// reduce split-K slices, scale by routing*LSCALE, pack bf16 into Xe extension cols
__global__ void scale_store_kernel(const float* __restrict__ D32,
                                   const float* __restrict__ rw,
                                   ushort* __restrict__ Xe) {
  int i = blockIdx.x * 256 + threadIdx.x;          // [0, TOK*NRANK/4)
  int t = i >> 5;                                  // token
  int g = (i & 31) * 4;                            // col base (4 cols, same expert)
  size_t base = (size_t)t * NRANK + g;
  const size_t ss = (size_t)TOK * NRANK;
  float4 a = *reinterpret_cast<const float4*>(D32 + base);
  float4 b = *reinterpret_cast<const float4*>(D32 + ss + base);
  float4 c = *reinterpret_cast<const float4*>(D32 + 2 * ss + base);
  float4 d = *reinterpret_cast<const float4*>(D32 + 3 * ss + base);
  int n = g >> 4;                                  // expert index
  int bb = t / SEQB;
  float s = rw[bb * NEXP + n] * LSCALE;
  union { ushort u[4]; uint2 v; } o;
  o.u[0] = f2bf((a.x + b.x + c.x + d.x) * s);
  o.u[1] = f2bf((a.y + b.y + c.y + d.y) * s);
  o.u[2] = f2bf((a.z + b.z + c.z + d.z) * s);
  o.u[3] = f2bf((a.w + b.w + c.w + d.w) * s);
  *reinterpret_cast<uint2*>(Xe + (size_t)t * KE + DIN + g) = o.v;
}

// ---------- 256x256 bf16 GEMM — reads INSIDE the MFMA regions ----------
// C[m,n] = sum_k A[m,k]*B[n,k], A:[TOK,KE], B:[DOUT,KE] (B^T), fp32 out.
// EXPERIMENT (single lever vs r5): in r1-r5 every ds_read burst sat in its
// OWN barrier-delimited region (all waves read -> barrier -> all waves MFMA),
// so LDS service and MFMA serialized by construction (serial-sum fit, 5 rounds).
// Now each region is {issue NEXT-phase ds_reads + STAGE, then MFMA on frags
// read in the PREVIOUS region}: the new reads have no consumer until the next
// region, so the LDS pipe services them WHILE the MFMA cluster drains (the
// m201 template's actual overlap mechanism). 2 barriers/window (was 4).
// No manual lgkm waits: the MFMAs' operands carry no dependency on the new
// reads, and the compiler places counted lgkm waits before first use.
// Ledger (4 DMA ops/window: A@p0, B@p1, both for tile T+3):
//   invariant at window-T start: tiles T AND T+1 resident (p1 region of T
//   reads tile T+1 frags). Prologue: stage 0,1,2 then vmcnt(4) -> 0,1 landed.
//   End-of-window vmcnt(4): outstanding {T+2(4), T+3(4)} -> drains T+2 ->
//   invariant holds for T+1. Tail (T >= NT-4): vmcnt(0).
// W-after-R: STAGE in window T targets slot (T+3)&3 = (T-1)&3; last reads of
// that slot issued in window T-1's p0 region and lgkm-drained by their MFMA
// consumers in T-1's p1 region — >= 1 barrier before the DMA lands. Race-free.
// Engine: 16x16x32 (r5-proven swizzle, 0 bank conflicts). Ping-pong frag sets
// with compile-time u indexing (rule #20), r4-proven.
#define BK32  32
#define NT132 (KE / BK32)    // 132

__global__ __launch_bounds__(512, 2)
void gemm256(const ushort* __restrict__ A, const ushort* __restrict__ Bm,
             float* __restrict__ C) {
  __shared__ __align__(16) ushort As[4][256 * 32];   // 64 KiB
  __shared__ __align__(16) ushort Bs[4][256 * 32];   // 64 KiB

  const int tid  = threadIdx.x;
  const int w    = tid >> 6;        // wave 0..7
  const int lane = tid & 63;
  const int wm   = w >> 2;          // 0..1  (M half)
  const int wn   = w & 3;           // 0..3  (N quarter)

  // XCD-aware rectangular chunks (round-2 proven: FETCH 557->203 MB).
  const int bid = blockIdx.x;
  const int xg  = bid & 7;
  const int jj  = bid >> 3;                            // 0..63
  const int bm  = (((xg & 3) << 3) + (jj & 7)) << 8;   // mi*256, mi 0..31
  const int bn  = (((xg >> 2) << 3) + (jj >> 3)) << 8; // ni*256, ni 0..15

  f4_t acc[8][4];
#pragma unroll
  for (int i = 0; i < 8; ++i)
#pragma unroll
    for (int q = 0; q < 4; ++q) acc[i][q] = (f4_t){0.f, 0.f, 0.f, 0.f};

  // ---- frag-read geometry (swizzled; r5-proven 0 conflicts) ----
  const int frow = lane & 15;
  const int cbs  = (((lane >> 4) ^ (frow >> 1)) << 4);
  const int ar0  = wm * 128;        // wave's A row base (rows)
  const int br0  = wn * 64;         // wave's B row base (rows)

  // ---- staging geometry (per-thread, tile = 256x32 bf16 = 16 KiB; proven) ----
  const int sxr = (lane >> 3) << 4;
  const int t0  = (w << 10) + (lane << 4);
  const int l0b = t0 ^ sxr;
  const int l1b = (t0 + 8192) ^ sxr;
  const size_t goff0 = (size_t)(l0b >> 6) * KE + ((l0b & 63) >> 1); // elements
  const size_t goff1 = (size_t)(l1b >> 6) * KE + ((l1b & 63) >> 1);
  const int ld0 = (w << 9);          // LDS dest base, elements
  const int ld1 = (w << 9) + 4096;

  const ushort* Ap = A  + (size_t)bm * KE;
  const ushort* Bp = Bm + (size_t)bn * KE;

#define STAGE_A256(kt, buf) do {                                   \
    const ushort* cp_ = Ap + (size_t)(kt) * BK32;                  \
    async_copy16(cp_ + goff0, (void*)(As[buf] + ld0));             \
    async_copy16(cp_ + goff1, (void*)(As[buf] + ld1));             \
  } while (0)
#define STAGE_B256(kt, buf) do {                                   \
    const ushort* cp_ = Bp + (size_t)(kt) * BK32;                  \
    async_copy16(cp_ + goff0, (void*)(Bs[buf] + ld0));             \
    async_copy16(cp_ + goff1, (void*)(Bs[buf] + ld1));             \
  } while (0)
// A-frag (mh half, index f_) / B-frag (index g_) read from slot s_
#define RD_A(s_, mh, f_) (*(const bf8_t*)((const char*)As[s_] + \
    (((ar0 + (mh) * 64 + (f_) * 16 + frow) << 6) ^ cbs)))
#define RD_B(s_, g_) (*(const bf8_t*)((const char*)Bs[s_] + \
    (((br0 + (g_) * 16 + frow) << 6) ^ cbs)))

  // prologue: stage tiles 0,1,2 (12 loads/thread); drain tiles 0 AND 1.
  STAGE_A256(0, 0); STAGE_B256(0, 0);
  STAGE_A256(1, 1); STAGE_B256(1, 1);
  STAGE_A256(2, 2); STAGE_B256(2, 2);
  asm volatile("s_waitcnt vmcnt(4)" ::: "memory");   // tiles 0,1 landed; 2 in flight
  __builtin_amdgcn_s_barrier();

  // ping-pong frag sets (static-indexed via unrolled u)
  bf8_t fA0[2][4], fA1[2][4], fB[2][4];
#pragma unroll
  for (int f = 0; f < 4; ++f) fA0[0][f] = RD_A(0, 0, f);
#pragma unroll
  for (int g = 0; g < 4; ++g) fB[0][g]  = RD_B(0, g);

  for (int t2 = 0; t2 < NT132; t2 += 2) {
#pragma unroll
    for (int u = 0; u < 2; ++u) {
      const int T  = t2 + u;
      const int b  = T & 3;
      const int b1 = (T + 1) & 3;
      const int sb = (T + 3) & 3;

      // ---- region p0: issue a1-reads (consumed in p1) + stage A(T+3);
      //      MFMA mh0 on frags read in the previous region ----
      __builtin_amdgcn_s_setprio(1);
#pragma unroll
      for (int f = 0; f < 4; ++f) fA1[u][f] = RD_A(b, 1, f);
      if (T + 3 < NT132) STAGE_A256(T + 3, sb);
#pragma unroll
      for (int f = 0; f < 4; ++f)
#pragma unroll
        for (int g = 0; g < 4; ++g)
          acc[f][g] = __builtin_amdgcn_mfma_f32_16x16x32_bf16(fA0[u][f], fB[u][g], acc[f][g], 0, 0, 0);
      __builtin_amdgcn_s_setprio(0);
      __builtin_amdgcn_s_barrier();

      // ---- region p1: issue tile-(T+1) a0+B reads (consumed next window's
      //      p0) + stage B(T+3); MFMA mh1 on a1 read in p0 ----
      __builtin_amdgcn_s_setprio(1);
      if (T + 1 < NT132) {
#pragma unroll
        for (int f = 0; f < 4; ++f) fA0[u ^ 1][f] = RD_A(b1, 0, f);
#pragma unroll
        for (int g = 0; g < 4; ++g) fB[u ^ 1][g]  = RD_B(b1, g);
      }
      if (T + 3 < NT132) STAGE_B256(T + 3, sb);
#pragma unroll
      for (int f = 0; f < 4; ++f)
#pragma unroll
        for (int g = 0; g < 4; ++g)
          acc[4 + f][g] = __builtin_amdgcn_mfma_f32_16x16x32_bf16(fA1[u][f], fB[u][g], acc[4 + f][g], 0, 0, 0);
      __builtin_amdgcn_s_setprio(0);
      // counted vmcnt: drain tile T+2's DMA (invariant: T+1, T+2 resident at
      // next window's start); keep T+3's 4 loads in flight.
      if (T < NT132 - 4) asm volatile("s_waitcnt vmcnt(4)" ::: "memory");
      else               asm volatile("s_waitcnt vmcnt(0)" ::: "memory");
      __builtin_amdgcn_s_barrier();
    }
  }

  // epilogue: fp32 C write (C/D layout: col = lane&15, row = (lane>>4)*4 + rr)
#pragma unroll
  for (int i = 0; i < 8; ++i) {
    int row = bm + wm * 128 + i * 16 + (lane >> 4) * 4;
#pragma unroll
    for (int q = 0; q < 4; ++q) {
      int col = bn + wn * 64 + q * 16 + (lane & 15);
#pragma unroll
      for (int rr = 0; rr < 4; ++rr)
        C[(size_t)(row + rr) * DOUT + col] = acc[i][q][rr];
    }
  }
#undef STAGE_A256
#undef STAGE_B256
#undef RD_A
#undef RD_B
}

extern "C" void kernel_launch(void* const* d_in, const int* in_sizes, int n_in,
                              void* d_out, int out_size, void* d_ws, size_t ws_size,
                              hipStream_t stream) {
  const float* x  = (const float*)d_in[0];
  const float* rw = (const float*)d_in[1];
  const float* wb = (const float*)d_in[2];
  const float* ld = (const float*)d_in[3];
  const float* lu = (const float*)d_in[4];
  float* out = (float*)d_out;

  // workspace layout (bf16 elements unless noted)
  ushort* Xe  = (ushort*)d_ws;                         // TOK*KE
  ushort* Wc  = Xe + (size_t)TOK * KE;                 // DOUT*KE
  ushort* Ldb = Wc + (size_t)DOUT * KE;                // NRANK*DIN
  float*  D32 = (float*)(Ldb + (size_t)NRANK * DIN);   // KSPLIT*TOK*NRANK fp32

  // one fused conversion dispatch (x, W_base, lora_up, lora_down -> bf16)
  cvt_all_kernel<<<RTOT / 256, 256, 0, stream>>>(x, wb, lu, ld, Xe, Wc, Ldb);

  // down-projection: D32[z] = Xe[:, z*1024:(z+1)*1024] @ Ld^T   (split-K)
  gemm128<KSLICE, DIN, 1><<<dim3(1, TOK / 128, KSPLIT), 256, 0, stream>>>(Xe, Ldb, D32);
  // reduce + routing scale + pack into Xe extension columns
  scale_store_kernel<<<TOK * NRANK / 4 / 256, 256, 0, stream>>>(D32, rw, Xe);
  // main GEMM: out = Xe[TOK,KE] @ Wc[DOUT,KE]^T  (reads-inside-MFMA-region)
  gemm256<<<dim3((TOK / 256) * (DOUT / 256)), 512, 0, stream>>>(Xe, Wc, out);
}